// Round 20
// baseline (107.506 us; speedup 1.0000x reference)
//
#include <hip/hip_runtime.h>
#include <hip/hip_bf16.h>

typedef __hip_bfloat16 bf16;
__device__ __forceinline__ float bf2f(bf16 v) { return __bfloat162float(v); }

typedef __attribute__((ext_vector_type(8))) short short8;
typedef __attribute__((ext_vector_type(4))) float floatx4;
typedef __attribute__((ext_vector_type(4))) int intx4;

#define EB_BITS 7            // 128 edge segments per coarse bucket (KB=255)
#define VB_BITS 10           // 1024 vertex segments per coarse bucket
#define MAXBK   256          // coarse bucket ceiling (157+98=255 here)
#define F1_ITEMS 2048        // incidences per bucketize block
#define XS_STRIDE 136        // ushort; gemm LDS row stride
#define SMEM_INTS 5892       // 23.6 KB union (bucketize: 772+4096 ints + 4096B)
#define HF_MAXIT 20          // histfill: max 20*1024 records/bucket (%4==0)

__device__ __forceinline__ int rbase(int b, int nEB, int capE, int capV) {
  return (b < nEB) ? b * capE : nEB * capE + (b - nEB) * capV;
}

// ===========================================================================
// Tiny zero kernel for gcursor.
// ===========================================================================
__global__ void zero_gc_kernel(int* __restrict__ gcursor) {
  gcursor[threadIdx.x] = 0;
}

// ===========================================================================
// Bucketize body — r11 proven: reservation-style (1 LDS atomic/record),
// delta gcursor, int4 input loads, staged coalesced copy-out.
// Record formats:  E: (e_local:7 <<17)|v   V: (v_local:10 <<17)|e
// ===========================================================================
__device__ void bucketize_body(int* smem4,
    const int* __restrict__ vertex, const int* __restrict__ edges,
    int* __restrict__ gcursor, int* __restrict__ records,
    int nnz, int KB, int nEB, int capE, int capV, int bb) {
  int* cnt    = smem4;            // 256
  int* scanEx = smem4 + 256;      // 256
  int* bases  = smem4 + 512;      // 256
  int* wsum4  = smem4 + 768;      // 4
  int* staged = smem4 + 772;      // 4096
  unsigned char* sbkt = (unsigned char*)(smem4 + 772 + 4096);  // 4096 B

  const int tid  = threadIdx.x;
  const int lane = tid & 63;
  const int wid  = tid >> 6;
  const int base = bb * F1_ITEMS;
  const int iEnd = min(nnz, base + F1_ITEMS);

  cnt[tid] = 0;
  __syncthreads();

  int recs[16], bks[16], ps[16];
  const int i0 = base + tid * 8;
  if (i0 + 7 < iEnd) {
    const intx4 ea = __builtin_nontemporal_load((const intx4*)&edges[i0]);
    const intx4 eb = __builtin_nontemporal_load((const intx4*)&edges[i0 + 4]);
    const intx4 va = __builtin_nontemporal_load((const intx4*)&vertex[i0]);
    const intx4 vb = __builtin_nontemporal_load((const intx4*)&vertex[i0 + 4]);
    const int ee[8] = {ea.x, ea.y, ea.z, ea.w, eb.x, eb.y, eb.z, eb.w};
    const int vv[8] = {va.x, va.y, va.z, va.w, vb.x, vb.y, vb.z, vb.w};
#pragma unroll
    for (int j = 0; j < 8; ++j) {
      const int e = ee[j], v = vv[j];
      const int bkE = e >> EB_BITS;
      const int bkV = nEB + (v >> VB_BITS);
      recs[2*j]   = ((e & ((1 << EB_BITS) - 1)) << 17) | v;
      bks[2*j]    = bkE;
      ps[2*j]     = atomicAdd(&cnt[bkE], 1);
      recs[2*j+1] = ((v & ((1 << VB_BITS) - 1)) << 17) | e;
      bks[2*j+1]  = bkV;
      ps[2*j+1]   = atomicAdd(&cnt[bkV], 1);
    }
  } else {
#pragma unroll
    for (int j = 0; j < 8; ++j) {
      const int i = i0 + j;
      if (i < iEnd) {
        const int e = edges[i];
        const int v = vertex[i];
        const int bkE = e >> EB_BITS;
        const int bkV = nEB + (v >> VB_BITS);
        recs[2*j]   = ((e & ((1 << EB_BITS) - 1)) << 17) | v;
        bks[2*j]    = bkE;
        ps[2*j]     = atomicAdd(&cnt[bkE], 1);
        recs[2*j+1] = ((v & ((1 << VB_BITS) - 1)) << 17) | e;
        bks[2*j+1]  = bkV;
        ps[2*j+1]   = atomicAdd(&cnt[bkV], 1);
      } else {
        bks[2*j] = -1;  bks[2*j+1] = -1;
      }
    }
  }
  __syncthreads();

  // Exclusive scan over 256 buckets: shfl wave-scan + 4-way cross-wave
  const int c = cnt[tid];
  int inc = c;
#pragma unroll
  for (int d = 1; d < 64; d <<= 1) {
    int t = __shfl_up(inc, d, 64);
    if (lane >= d) inc += t;
  }
  if (lane == 63) wsum4[wid] = inc;
  __syncthreads();
  if (tid < 4) {
    int wv = wsum4[tid];
#pragma unroll
    for (int d = 1; d < 4; d <<= 1) {
      int t = __shfl_up(wv, d, 64);
      if (tid >= d) wv += t;
    }
    wsum4[tid] = wv;
  }
  __syncthreads();
  const int excl = inc - c + (wid > 0 ? wsum4[wid - 1] : 0);

  if (tid < KB && c > 0)
    bases[tid] = rbase(tid, nEB, capE, capV) + atomicAdd(&gcursor[tid], c);
  scanEx[tid] = excl;
  __syncthreads();

  // Placement: plain LDS stores (reservation already holds the slot)
#pragma unroll
  for (int j = 0; j < 16; ++j) {
    if (bks[j] >= 0) {
      const int s = scanEx[bks[j]] + ps[j];
      staged[s] = recs[j];
      sbkt[s] = (unsigned char)bks[j];
    }
  }
  __syncthreads();

  // Coalesced copy-out (sequential per-run stores)
  const int nrec = 2 * (iEnd - base);
  for (int s = tid; s < nrec; s += 256) {
    const int b = sbkt[s];
    records[bases[b] + (s - scanEx[b])] = staged[s];
  }
}

// ===========================================================================
// GEMM body (r5-r19 proven; verified layouts learn_hip m89/m120)
// ===========================================================================
__device__ __forceinline__ unsigned int pack_bf16x2(float lo, float hi) {
  bf16 a = __float2bfloat16(lo);
  bf16 b = __float2bfloat16(hi);
  unsigned short ua = *(unsigned short*)&a;
  unsigned short ub = *(unsigned short*)&b;
  return (unsigned int)ua | ((unsigned int)ub << 16);
}

__device__ void gemm_body(int* smem4,
    const float* __restrict__ X, const float* __restrict__ W,
    bf16* __restrict__ Xl, int Nrows, int ntiles, int gb, int GB) {
  unsigned short* S = (unsigned short*)smem4;   // Ws, then Xs (17.4 KB)

  const int tid  = threadIdx.x;
  const int wave = tid >> 6;
  const int lane = tid & 63;
  const int quad = lane >> 4;
  const int l15  = lane & 15;

  for (int i = tid; i < 8192; i += 256) {
    const int k = i >> 6, n = i & 63;
    bf16 h = __float2bfloat16(W[i]);
    S[n * XS_STRIDE + k] = *(unsigned short*)&h;
  }
  __syncthreads();

  short8 bfrag[4][4];
#pragma unroll
  for (int ct = 0; ct < 4; ++ct)
#pragma unroll
    for (int kt = 0; kt < 4; ++kt)
      bfrag[ct][kt] = *(const short8*)&S[(ct * 16 + l15) * XS_STRIDE + kt * 32 + quad * 8];
  __syncthreads();   // done with Ws; S becomes Xs

  const int r  = tid >> 2;
  const int c0 = (tid & 3) * 32;

  for (int tile = gb; tile < ntiles; tile += GB) {
    const int row0 = tile * 64;
    {
      int rr = row0 + r;
      if (rr >= Nrows) rr = Nrows - 1;
      const float* src = X + (size_t)rr * 128 + c0;
      unsigned short* dst = &S[r * XS_STRIDE + c0];
#pragma unroll
      for (int q = 0; q < 4; ++q) {
        const float4 f0 = *(const float4*)(src + q * 8);
        const float4 f1 = *(const float4*)(src + q * 8 + 4);
        uint4 o;
        o.x = pack_bf16x2(f0.x, f0.y);
        o.y = pack_bf16x2(f0.z, f0.w);
        o.z = pack_bf16x2(f1.x, f1.y);
        o.w = pack_bf16x2(f1.z, f1.w);
        *(uint4*)(dst + q * 8) = o;
      }
    }
    __syncthreads();

    const int m = wave * 16 + l15;
    short8 afrag[4];
#pragma unroll
    for (int kt = 0; kt < 4; ++kt)
      afrag[kt] = *(const short8*)&S[m * XS_STRIDE + kt * 32 + quad * 8];

    floatx4 acc[4];
#pragma unroll
    for (int ct = 0; ct < 4; ++ct) {
      acc[ct] = (floatx4){0.f, 0.f, 0.f, 0.f};
#pragma unroll
      for (int kt = 0; kt < 4; ++kt)
        acc[ct] = __builtin_amdgcn_mfma_f32_16x16x32_bf16(
            afrag[kt], bfrag[ct][kt], acc[ct], 0, 0, 0);
    }

    const int rbase_ = row0 + wave * 16 + quad * 4;
#pragma unroll
    for (int ct = 0; ct < 4; ++ct) {
      const int col = ct * 16 + l15;
#pragma unroll
      for (int reg = 0; reg < 4; ++reg) {
        const int row = rbase_ + reg;
        if (row < Nrows) Xl[(size_t)row * 64 + col] = __float2bfloat16(acc[ct][reg]);
      }
    }
    __syncthreads();
  }
}

// ===========================================================================
// K1: GEMM first, bucketize fills remaining CU capacity (r14/r15 A/B:
// fusion = +16us real overlap; gemm rides ~free under bucketize).
// ===========================================================================
__global__ __launch_bounds__(256) void fused1_kernel(
    const int* __restrict__ vertex, const int* __restrict__ edges,
    int* __restrict__ gcursor, int* __restrict__ records,
    const float* __restrict__ X, const float* __restrict__ W,
    bf16* __restrict__ Xl,
    int nnz, int KB, int nEB, int capE, int capV, int Nrows, int ntiles, int GB) {
  __shared__ int smem4[SMEM_INTS];   // 23.6 KB union
  if ((int)blockIdx.x < GB)
    gemm_body(smem4, X, W, Xl, Nrows, ntiles, blockIdx.x, GB);
  else
    bucketize_body(smem4, vertex, edges, gcursor, records, nnz, KB, nEB,
                   capE, capV, blockIdx.x - GB);
}

// ===========================================================================
// K2: combined histfill, one block per bucket. Reservation-style, int4
// pass-1 record loads, inline cross-bucket scan from delta gcursor.
// ===========================================================================
__global__ __launch_bounds__(1024) void histfill_kernel(
    const int* __restrict__ records, const int* __restrict__ gcursor,
    int* __restrict__ offs, int* __restrict__ perm,
    int nEB, int capE, int capV, int E, int M, int KB, int totrec) {
  __shared__ int cnt[1 << VB_BITS];
  __shared__ int wsum[16];
  const int b    = blockIdx.x;
  const int tid  = threadIdx.x;
  const int lane = tid & 63;
  const int wid  = tid >> 6;

  const int base = rbase(b, nEB, capE, capV);
  const int end  = base + gcursor[b];

  // ---- inline cross-bucket exclusive scan over delta totals ----
  int bb = 0;
  {
    const int tot = (tid < KB) ? gcursor[tid] : 0;
    int inc = tot;
    if (tid < 256) {
#pragma unroll
      for (int d = 1; d < 64; d <<= 1) {
        const int t = __shfl_up(inc, d, 64);
        if (lane >= d) inc += t;
      }
      if (lane == 63) wsum[wid] = inc;
    }
    __syncthreads();
    if (tid < 256) {
      int wbase = 0;
      for (int w = 0; w < wid; ++w) wbase += wsum[w];
      cnt[tid] = wbase + inc - tot;
    }
    __syncthreads();
    bb = cnt[b];
    __syncthreads();
  }
  if (b == 0 && tid == 0) offs[M] = totrec;   // == 2*nnz

  cnt[tid] = 0;
  __syncthreads();

  // pass1: int4 read + reserve (records read ONCE; 5 vector iters = 20480)
  int myrec[HF_MAXIT], myp[HF_MAXIT];
#pragma unroll
  for (int it = 0; it < HF_MAXIT / 4; ++it) {
    const int r = base + (tid + it * 1024) * 4;
    if (r + 3 < end) {
      const intx4 rv = __builtin_nontemporal_load((const intx4*)&records[r]);
      myrec[4*it+0] = rv.x;  myp[4*it+0] = atomicAdd(&cnt[rv.x >> 17], 1);
      myrec[4*it+1] = rv.y;  myp[4*it+1] = atomicAdd(&cnt[rv.y >> 17], 1);
      myrec[4*it+2] = rv.z;  myp[4*it+2] = atomicAdd(&cnt[rv.z >> 17], 1);
      myrec[4*it+3] = rv.w;  myp[4*it+3] = atomicAdd(&cnt[rv.w >> 17], 1);
    } else {
#pragma unroll
      for (int k = 0; k < 4; ++k) {
        const int rr = r + k;
        if (rr < end) {
          const int rec = records[rr];
          myrec[4*it+k] = rec;
          myp[4*it+k] = atomicAdd(&cnt[rec >> 17], 1);
        } else {
          myrec[4*it+k] = -1;
        }
      }
    }
  }
  __syncthreads();

  // 1024-wide exclusive scan (shfl wave-scan + 16-way cross-wave)
  const int c = cnt[tid];
  int inc = c;
#pragma unroll
  for (int d = 1; d < 64; d <<= 1) {
    const int t = __shfl_up(inc, d, 64);
    if (lane >= d) inc += t;
  }
  if (lane == 63) wsum[wid] = inc;
  __syncthreads();
  if (tid < 16) {
    int wv = wsum[tid];
#pragma unroll
    for (int d = 1; d < 16; d <<= 1) {
      const int t = __shfl_up(wv, d, 64);
      if (tid >= d) wv += t;
    }
    wsum[tid] = wv;
  }
  __syncthreads();
  const int goff = bb + inc - c + (wid > 0 ? wsum[wid - 1] : 0);

  int seg_lo, segN;
  if (b < nEB) { seg_lo = b << EB_BITS;               segN = min(E - seg_lo, 1 << EB_BITS); }
  else         { seg_lo = E + ((b - nEB) << VB_BITS); segN = min(M - seg_lo, 1 << VB_BITS); }
  if (tid < segN) offs[seg_lo + tid] = goff;
  cnt[tid] = goff;   // exclusive bases (plain reads in pass2)
  __syncthreads();

  // pass2: plain stores
#pragma unroll
  for (int it = 0; it < HF_MAXIT; ++it) {
    if (myrec[it] >= 0)
      perm[cnt[myrec[it] >> 17] + myp[it]] = myrec[it] & 0x1FFFF;
  }
}

// ===========================================================================
// K3: gather_e — one wave per 2 CONSECUTIVE edges (r19's grouped-segment
// form generalized; fixed per-segment chain amortized, shared perm chunk).
// ===========================================================================
__global__ __launch_bounds__(256) void gather_e_kernel(
    const bf16* __restrict__ Xl, const int* __restrict__ perm,
    const int* __restrict__ offs, const float* __restrict__ degE,
    const float* __restrict__ W_edge, bf16* __restrict__ Xe, int E) {
  const int wave = (blockIdx.x * 256 + threadIdx.x) >> 6;
  const int lane = threadIdx.x & 63;
  const int e0   = wave * 2;
  if (e0 >= E) return;
  const int ne = min(2, E - e0);

  const int   offv = (lane <= ne) ? offs[e0 + lane] : 0;
  const float sv   = (lane < ne) ? degE[e0 + lane] * W_edge[e0 + lane] : 0.f;
  const int wend = __shfl(offv, ne, 64);
  int cb  = __shfl(offv, 0, 64);
  int idx = (cb + lane < wend) ? __builtin_nontemporal_load(&perm[cb + lane]) : 0;

  for (int k = 0; k < ne; ++k) {
    const int beg = __shfl(offv, k, 64);
    const int end = __shfl(offv, k + 1, 64);
    float acc = 0.f;
    int j = beg;
    while (j < end) {
      if (j - cb >= 64) {
        cb += 64;
        idx = (cb + lane < wend) ? __builtin_nontemporal_load(&perm[cb + lane]) : 0;
        continue;
      }
      const int lim = min(end, cb + 64);
      for (; j + 8 <= lim; j += 8) {
        const bf16* p0 = &Xl[(size_t)__shfl(idx, j - cb + 0, 64) * 64 + lane];
        const bf16* p1 = &Xl[(size_t)__shfl(idx, j - cb + 1, 64) * 64 + lane];
        const bf16* p2 = &Xl[(size_t)__shfl(idx, j - cb + 2, 64) * 64 + lane];
        const bf16* p3 = &Xl[(size_t)__shfl(idx, j - cb + 3, 64) * 64 + lane];
        const bf16* p4 = &Xl[(size_t)__shfl(idx, j - cb + 4, 64) * 64 + lane];
        const bf16* p5 = &Xl[(size_t)__shfl(idx, j - cb + 5, 64) * 64 + lane];
        const bf16* p6 = &Xl[(size_t)__shfl(idx, j - cb + 6, 64) * 64 + lane];
        const bf16* p7 = &Xl[(size_t)__shfl(idx, j - cb + 7, 64) * 64 + lane];
        const float f0 = bf2f(*p0), f1 = bf2f(*p1), f2 = bf2f(*p2), f3 = bf2f(*p3);
        const float f4 = bf2f(*p4), f5 = bf2f(*p5), f6 = bf2f(*p6), f7 = bf2f(*p7);
        acc += ((f0 + f1) + (f2 + f3)) + ((f4 + f5) + (f6 + f7));
      }
      for (; j + 4 <= lim; j += 4) {
        const int v0 = __shfl(idx, j - cb + 0, 64);
        const int v1 = __shfl(idx, j - cb + 1, 64);
        const int v2 = __shfl(idx, j - cb + 2, 64);
        const int v3 = __shfl(idx, j - cb + 3, 64);
        const float f0 = bf2f(Xl[(size_t)v0 * 64 + lane]);
        const float f1 = bf2f(Xl[(size_t)v1 * 64 + lane]);
        const float f2 = bf2f(Xl[(size_t)v2 * 64 + lane]);
        const float f3 = bf2f(Xl[(size_t)v3 * 64 + lane]);
        acc += (f0 + f1) + (f2 + f3);
      }
      for (; j < lim; ++j) {
        const int v = __shfl(idx, j - cb, 64);
        acc += bf2f(Xl[(size_t)v * 64 + lane]);
      }
    }
    const float s = __shfl(sv, k, 64);
    Xe[(size_t)(e0 + k) * 64 + lane] = __float2bfloat16(acc * s);
  }
}

// ===========================================================================
// K4: gather_v — one wave per 8 CONSECUTIVE nodes (r19 proven at 4; fixed
// per-node chain amortized further; avg group window 80 ~= 2 chunks).
// ===========================================================================
__global__ __launch_bounds__(256) void gather_v_kernel(
    const bf16* __restrict__ Xe, const int* __restrict__ perm,
    const int* __restrict__ offs, const float* __restrict__ degV,
    float* __restrict__ out, int N, int E) {
  const int wave = (blockIdx.x * 256 + threadIdx.x) >> 6;
  const int lane = threadIdx.x & 63;
  const int v0   = wave * 8;
  if (v0 >= N) return;
  const int nv = min(8, N - v0);

  const int   offv = (lane <= nv) ? offs[E + v0 + lane] : 0;
  const float dv   = (lane < nv) ? degV[v0 + lane] : 0.f;
  const int wend = __shfl(offv, nv, 64);
  int cb  = __shfl(offv, 0, 64);
  int idx = (cb + lane < wend) ? __builtin_nontemporal_load(&perm[cb + lane]) : 0;

  for (int k = 0; k < nv; ++k) {
    const int beg = __shfl(offv, k, 64);
    const int end = __shfl(offv, k + 1, 64);
    float acc = 0.f;
    int j = beg;
    while (j < end) {
      if (j - cb >= 64) {
        cb += 64;
        idx = (cb + lane < wend) ? __builtin_nontemporal_load(&perm[cb + lane]) : 0;
        continue;
      }
      const int lim = min(end, cb + 64);
      for (; j + 4 <= lim; j += 4) {
        const int e0 = __shfl(idx, j - cb + 0, 64);
        const int e1 = __shfl(idx, j - cb + 1, 64);
        const int e2 = __shfl(idx, j - cb + 2, 64);
        const int e3 = __shfl(idx, j - cb + 3, 64);
        const float f0 = bf2f(Xe[(size_t)e0 * 64 + lane]);
        const float f1 = bf2f(Xe[(size_t)e1 * 64 + lane]);
        const float f2 = bf2f(Xe[(size_t)e2 * 64 + lane]);
        const float f3 = bf2f(Xe[(size_t)e3 * 64 + lane]);
        acc += (f0 + f1) + (f2 + f3);
      }
      for (; j < lim; ++j) {
        const int e = __shfl(idx, j - cb, 64);
        acc += bf2f(Xe[(size_t)e * 64 + lane]);
      }
    }
    const float d = __shfl(dv, k, 64);
    __builtin_nontemporal_store(acc * d, &out[(size_t)(v0 + k) * 64 + lane]);
  }
}

// ===========================================================================
extern "C" void kernel_launch(void* const* d_in, const int* in_sizes, int n_in,
                              void* d_out, int out_size, void* d_ws, size_t ws_size,
                              hipStream_t stream) {
  const float* X      = (const float*)d_in[0];
  const int*   vertex = (const int*)d_in[1];
  const int*   edges  = (const int*)d_in[2];
  const float* W      = (const float*)d_in[3];
  const float* degE   = (const float*)d_in[4];
  const float* degV   = (const float*)d_in[5];
  const float* W_edge = (const float*)d_in[6];
  float* out = (float*)d_out;

  const int nnz = in_sizes[1];
  const int E   = in_sizes[4];
  const int N   = in_sizes[5];
  const int M   = E + N;

  const int nEB = (E + (1 << EB_BITS) - 1) >> EB_BITS;
  const int nVB = (N + (1 << VB_BITS) - 1) >> VB_BITS;
  const int KB  = nEB + nVB;

  // caps: <= HF_MAXIT*1024 (histfill register carry) and %4==0 (int4 loads)
  int capE = (nnz / nEB) * 3 / 2 + 256;
  int capV = (nnz / nVB) * 3 / 2 + 256;
  if (capE > HF_MAXIT * 1024) capE = HF_MAXIT * 1024;
  if (capV > HF_MAXIT * 1024) capV = HF_MAXIT * 1024;
  capE = (capE + 3) & ~3;
  capV = (capV + 3) & ~3;
  const size_t rec_total = (size_t)nEB * capE + (size_t)nVB * capV;

  char* p = (char*)d_ws;
  auto alloc = [&](size_t bytes) -> void* {
    void* r = (void*)p;
    p += (bytes + 255) & ~(size_t)255;
    return r;
  };
  int*  offs    = (int*)alloc((size_t)(M + 1) * 4);
  int*  gcursor = (int*)alloc(MAXBK * 4);
  int*  perm    = (int*)alloc((size_t)2 * nnz * 4);   //  8 MB
  int*  records = (int*)alloc(rec_total * 4);         // ~12 MB (live w/ Xl)
  bf16* Xl      = (bf16*)alloc((size_t)N * 64 * 2);   // 12.8 MB
  bf16* Xe      = (bf16*)alloc((size_t)E * 64 * 2);   //  2.56 MB

  const int f1blocks = (nnz + F1_ITEMS - 1) / F1_ITEMS;
  const int ntiles   = (N + 63) / 64;
  const int GB       = ntiles < 512 ? ntiles : 512;
  const int ewaves   = (E + 1) / 2;                   // gather_e waves (2 edges/wave)
  const int vwaves   = (N + 7) / 8;                   // gather_v waves (8 nodes/wave)

  zero_gc_kernel<<<1, MAXBK, 0, stream>>>(gcursor);
  fused1_kernel<<<GB + f1blocks, 256, 0, stream>>>(
      vertex, edges, gcursor, records, X, W, Xl,
      nnz, KB, nEB, capE, capV, N, ntiles, GB);
  histfill_kernel<<<KB, 1024, 0, stream>>>(records, gcursor, offs, perm,
                                           nEB, capE, capV, E, M, KB, 2 * nnz);
  gather_e_kernel<<<(ewaves + 3) / 4, 256, 0, stream>>>(Xl, perm, offs, degE, W_edge, Xe, E);
  gather_v_kernel<<<(vwaves + 3) / 4, 256, 0, stream>>>(Xe, perm, offs, degV, out, N, E);
}

// Round 21
// 97.582 us; speedup vs baseline: 1.1017x; 1.1017x over previous
//
#include <hip/hip_runtime.h>
#include <hip/hip_bf16.h>

typedef __hip_bfloat16 bf16;
__device__ __forceinline__ float bf2f(bf16 v) { return __bfloat162float(v); }

typedef __attribute__((ext_vector_type(8))) short short8;
typedef __attribute__((ext_vector_type(4))) float floatx4;
typedef __attribute__((ext_vector_type(4))) int intx4;

#define EB_BITS 7            // 128 edge segments per coarse bucket (KB=255)
#define VB_BITS 10           // 1024 vertex segments per coarse bucket
#define MAXBK   256          // coarse bucket ceiling (157+98=255 here)
#define F1_ITEMS 2048        // incidences per bucketize block
#define XS_STRIDE 136        // ushort; gemm LDS row stride
#define SMEM_INTS 5892       // 23.6 KB union (bucketize: 772+4096 ints + 4096B)
#define HF_MAXIT 20          // histfill: max 20*1024 records/bucket (%4==0)

__device__ __forceinline__ int rbase(int b, int nEB, int capE, int capV) {
  return (b < nEB) ? b * capE : nEB * capE + (b - nEB) * capV;
}

// ===========================================================================
// Tiny zero kernel for gcursor.
// ===========================================================================
__global__ void zero_gc_kernel(int* __restrict__ gcursor) {
  gcursor[threadIdx.x] = 0;
}

// ===========================================================================
// Bucketize body — r11 proven: reservation-style (1 LDS atomic/record),
// delta gcursor, int4 input loads, staged coalesced copy-out.
// Record formats:  E: (e_local:7 <<17)|v   V: (v_local:10 <<17)|e
// ===========================================================================
__device__ void bucketize_body(int* smem4,
    const int* __restrict__ vertex, const int* __restrict__ edges,
    int* __restrict__ gcursor, int* __restrict__ records,
    int nnz, int KB, int nEB, int capE, int capV, int bb) {
  int* cnt    = smem4;            // 256
  int* scanEx = smem4 + 256;      // 256
  int* bases  = smem4 + 512;      // 256
  int* wsum4  = smem4 + 768;      // 4
  int* staged = smem4 + 772;      // 4096
  unsigned char* sbkt = (unsigned char*)(smem4 + 772 + 4096);  // 4096 B

  const int tid  = threadIdx.x;
  const int lane = tid & 63;
  const int wid  = tid >> 6;
  const int base = bb * F1_ITEMS;
  const int iEnd = min(nnz, base + F1_ITEMS);

  cnt[tid] = 0;
  __syncthreads();

  int recs[16], bks[16], ps[16];
  const int i0 = base + tid * 8;
  if (i0 + 7 < iEnd) {
    const intx4 ea = __builtin_nontemporal_load((const intx4*)&edges[i0]);
    const intx4 eb = __builtin_nontemporal_load((const intx4*)&edges[i0 + 4]);
    const intx4 va = __builtin_nontemporal_load((const intx4*)&vertex[i0]);
    const intx4 vb = __builtin_nontemporal_load((const intx4*)&vertex[i0 + 4]);
    const int ee[8] = {ea.x, ea.y, ea.z, ea.w, eb.x, eb.y, eb.z, eb.w};
    const int vv[8] = {va.x, va.y, va.z, va.w, vb.x, vb.y, vb.z, vb.w};
#pragma unroll
    for (int j = 0; j < 8; ++j) {
      const int e = ee[j], v = vv[j];
      const int bkE = e >> EB_BITS;
      const int bkV = nEB + (v >> VB_BITS);
      recs[2*j]   = ((e & ((1 << EB_BITS) - 1)) << 17) | v;
      bks[2*j]    = bkE;
      ps[2*j]     = atomicAdd(&cnt[bkE], 1);
      recs[2*j+1] = ((v & ((1 << VB_BITS) - 1)) << 17) | e;
      bks[2*j+1]  = bkV;
      ps[2*j+1]   = atomicAdd(&cnt[bkV], 1);
    }
  } else {
#pragma unroll
    for (int j = 0; j < 8; ++j) {
      const int i = i0 + j;
      if (i < iEnd) {
        const int e = edges[i];
        const int v = vertex[i];
        const int bkE = e >> EB_BITS;
        const int bkV = nEB + (v >> VB_BITS);
        recs[2*j]   = ((e & ((1 << EB_BITS) - 1)) << 17) | v;
        bks[2*j]    = bkE;
        ps[2*j]     = atomicAdd(&cnt[bkE], 1);
        recs[2*j+1] = ((v & ((1 << VB_BITS) - 1)) << 17) | e;
        bks[2*j+1]  = bkV;
        ps[2*j+1]   = atomicAdd(&cnt[bkV], 1);
      } else {
        bks[2*j] = -1;  bks[2*j+1] = -1;
      }
    }
  }
  __syncthreads();

  // Exclusive scan over 256 buckets: shfl wave-scan + 4-way cross-wave
  const int c = cnt[tid];
  int inc = c;
#pragma unroll
  for (int d = 1; d < 64; d <<= 1) {
    int t = __shfl_up(inc, d, 64);
    if (lane >= d) inc += t;
  }
  if (lane == 63) wsum4[wid] = inc;
  __syncthreads();
  if (tid < 4) {
    int wv = wsum4[tid];
#pragma unroll
    for (int d = 1; d < 4; d <<= 1) {
      int t = __shfl_up(wv, d, 64);
      if (tid >= d) wv += t;
    }
    wsum4[tid] = wv;
  }
  __syncthreads();
  const int excl = inc - c + (wid > 0 ? wsum4[wid - 1] : 0);

  if (tid < KB && c > 0)
    bases[tid] = rbase(tid, nEB, capE, capV) + atomicAdd(&gcursor[tid], c);
  scanEx[tid] = excl;
  __syncthreads();

  // Placement: plain LDS stores (reservation already holds the slot)
#pragma unroll
  for (int j = 0; j < 16; ++j) {
    if (bks[j] >= 0) {
      const int s = scanEx[bks[j]] + ps[j];
      staged[s] = recs[j];
      sbkt[s] = (unsigned char)bks[j];
    }
  }
  __syncthreads();

  // Coalesced copy-out (sequential per-run stores)
  const int nrec = 2 * (iEnd - base);
  for (int s = tid; s < nrec; s += 256) {
    const int b = sbkt[s];
    records[bases[b] + (s - scanEx[b])] = staged[s];
  }
}

// ===========================================================================
// GEMM body (r5-r19 proven; verified layouts learn_hip m89/m120)
// ===========================================================================
__device__ __forceinline__ unsigned int pack_bf16x2(float lo, float hi) {
  bf16 a = __float2bfloat16(lo);
  bf16 b = __float2bfloat16(hi);
  unsigned short ua = *(unsigned short*)&a;
  unsigned short ub = *(unsigned short*)&b;
  return (unsigned int)ua | ((unsigned int)ub << 16);
}

__device__ void gemm_body(int* smem4,
    const float* __restrict__ X, const float* __restrict__ W,
    bf16* __restrict__ Xl, int Nrows, int ntiles, int gb, int GB) {
  unsigned short* S = (unsigned short*)smem4;   // Ws, then Xs (17.4 KB)

  const int tid  = threadIdx.x;
  const int wave = tid >> 6;
  const int lane = tid & 63;
  const int quad = lane >> 4;
  const int l15  = lane & 15;

  for (int i = tid; i < 8192; i += 256) {
    const int k = i >> 6, n = i & 63;
    bf16 h = __float2bfloat16(W[i]);
    S[n * XS_STRIDE + k] = *(unsigned short*)&h;
  }
  __syncthreads();

  short8 bfrag[4][4];
#pragma unroll
  for (int ct = 0; ct < 4; ++ct)
#pragma unroll
    for (int kt = 0; kt < 4; ++kt)
      bfrag[ct][kt] = *(const short8*)&S[(ct * 16 + l15) * XS_STRIDE + kt * 32 + quad * 8];
  __syncthreads();   // done with Ws; S becomes Xs

  const int r  = tid >> 2;
  const int c0 = (tid & 3) * 32;

  for (int tile = gb; tile < ntiles; tile += GB) {
    const int row0 = tile * 64;
    {
      int rr = row0 + r;
      if (rr >= Nrows) rr = Nrows - 1;
      const float* src = X + (size_t)rr * 128 + c0;
      unsigned short* dst = &S[r * XS_STRIDE + c0];
#pragma unroll
      for (int q = 0; q < 4; ++q) {
        const float4 f0 = *(const float4*)(src + q * 8);
        const float4 f1 = *(const float4*)(src + q * 8 + 4);
        uint4 o;
        o.x = pack_bf16x2(f0.x, f0.y);
        o.y = pack_bf16x2(f0.z, f0.w);
        o.z = pack_bf16x2(f1.x, f1.y);
        o.w = pack_bf16x2(f1.z, f1.w);
        *(uint4*)(dst + q * 8) = o;
      }
    }
    __syncthreads();

    const int m = wave * 16 + l15;
    short8 afrag[4];
#pragma unroll
    for (int kt = 0; kt < 4; ++kt)
      afrag[kt] = *(const short8*)&S[m * XS_STRIDE + kt * 32 + quad * 8];

    floatx4 acc[4];
#pragma unroll
    for (int ct = 0; ct < 4; ++ct) {
      acc[ct] = (floatx4){0.f, 0.f, 0.f, 0.f};
#pragma unroll
      for (int kt = 0; kt < 4; ++kt)
        acc[ct] = __builtin_amdgcn_mfma_f32_16x16x32_bf16(
            afrag[kt], bfrag[ct][kt], acc[ct], 0, 0, 0);
    }

    const int rbase_ = row0 + wave * 16 + quad * 4;
#pragma unroll
    for (int ct = 0; ct < 4; ++ct) {
      const int col = ct * 16 + l15;
#pragma unroll
      for (int reg = 0; reg < 4; ++reg) {
        const int row = rbase_ + reg;
        if (row < Nrows) Xl[(size_t)row * 64 + col] = __float2bfloat16(acc[ct][reg]);
      }
    }
    __syncthreads();
  }
}

// ===========================================================================
// K1: GEMM first, bucketize fills remaining CU capacity (r14/r15 A/B:
// fusion = +16us real overlap; gemm rides ~free under bucketize).
// ===========================================================================
__global__ __launch_bounds__(256) void fused1_kernel(
    const int* __restrict__ vertex, const int* __restrict__ edges,
    int* __restrict__ gcursor, int* __restrict__ records,
    const float* __restrict__ X, const float* __restrict__ W,
    bf16* __restrict__ Xl,
    int nnz, int KB, int nEB, int capE, int capV, int Nrows, int ntiles, int GB) {
  __shared__ int smem4[SMEM_INTS];   // 23.6 KB union
  if ((int)blockIdx.x < GB)
    gemm_body(smem4, X, W, Xl, Nrows, ntiles, blockIdx.x, GB);
  else
    bucketize_body(smem4, vertex, edges, gcursor, records, nnz, KB, nEB,
                   capE, capV, blockIdx.x - GB);
}

// ===========================================================================
// K2: combined histfill, one block per bucket. Reservation-style, int4
// pass-1 record loads, inline cross-bucket scan from delta gcursor.
// ===========================================================================
__global__ __launch_bounds__(1024) void histfill_kernel(
    const int* __restrict__ records, const int* __restrict__ gcursor,
    int* __restrict__ offs, int* __restrict__ perm,
    int nEB, int capE, int capV, int E, int M, int KB, int totrec) {
  __shared__ int cnt[1 << VB_BITS];
  __shared__ int wsum[16];
  const int b    = blockIdx.x;
  const int tid  = threadIdx.x;
  const int lane = tid & 63;
  const int wid  = tid >> 6;

  const int base = rbase(b, nEB, capE, capV);
  const int end  = base + gcursor[b];

  // ---- inline cross-bucket exclusive scan over delta totals ----
  int bb = 0;
  {
    const int tot = (tid < KB) ? gcursor[tid] : 0;
    int inc = tot;
    if (tid < 256) {
#pragma unroll
      for (int d = 1; d < 64; d <<= 1) {
        const int t = __shfl_up(inc, d, 64);
        if (lane >= d) inc += t;
      }
      if (lane == 63) wsum[wid] = inc;
    }
    __syncthreads();
    if (tid < 256) {
      int wbase = 0;
      for (int w = 0; w < wid; ++w) wbase += wsum[w];
      cnt[tid] = wbase + inc - tot;
    }
    __syncthreads();
    bb = cnt[b];
    __syncthreads();
  }
  if (b == 0 && tid == 0) offs[M] = totrec;   // == 2*nnz

  cnt[tid] = 0;
  __syncthreads();

  // pass1: int4 read + reserve (records read ONCE; 5 vector iters = 20480)
  int myrec[HF_MAXIT], myp[HF_MAXIT];
#pragma unroll
  for (int it = 0; it < HF_MAXIT / 4; ++it) {
    const int r = base + (tid + it * 1024) * 4;
    if (r + 3 < end) {
      const intx4 rv = __builtin_nontemporal_load((const intx4*)&records[r]);
      myrec[4*it+0] = rv.x;  myp[4*it+0] = atomicAdd(&cnt[rv.x >> 17], 1);
      myrec[4*it+1] = rv.y;  myp[4*it+1] = atomicAdd(&cnt[rv.y >> 17], 1);
      myrec[4*it+2] = rv.z;  myp[4*it+2] = atomicAdd(&cnt[rv.z >> 17], 1);
      myrec[4*it+3] = rv.w;  myp[4*it+3] = atomicAdd(&cnt[rv.w >> 17], 1);
    } else {
#pragma unroll
      for (int k = 0; k < 4; ++k) {
        const int rr = r + k;
        if (rr < end) {
          const int rec = records[rr];
          myrec[4*it+k] = rec;
          myp[4*it+k] = atomicAdd(&cnt[rec >> 17], 1);
        } else {
          myrec[4*it+k] = -1;
        }
      }
    }
  }
  __syncthreads();

  // 1024-wide exclusive scan (shfl wave-scan + 16-way cross-wave)
  const int c = cnt[tid];
  int inc = c;
#pragma unroll
  for (int d = 1; d < 64; d <<= 1) {
    const int t = __shfl_up(inc, d, 64);
    if (lane >= d) inc += t;
  }
  if (lane == 63) wsum[wid] = inc;
  __syncthreads();
  if (tid < 16) {
    int wv = wsum[tid];
#pragma unroll
    for (int d = 1; d < 16; d <<= 1) {
      const int t = __shfl_up(wv, d, 64);
      if (tid >= d) wv += t;
    }
    wsum[tid] = wv;
  }
  __syncthreads();
  const int goff = bb + inc - c + (wid > 0 ? wsum[wid - 1] : 0);

  int seg_lo, segN;
  if (b < nEB) { seg_lo = b << EB_BITS;               segN = min(E - seg_lo, 1 << EB_BITS); }
  else         { seg_lo = E + ((b - nEB) << VB_BITS); segN = min(M - seg_lo, 1 << VB_BITS); }
  if (tid < segN) offs[seg_lo + tid] = goff;
  cnt[tid] = goff;   // exclusive bases (plain reads in pass2)
  __syncthreads();

  // pass2: plain stores
#pragma unroll
  for (int it = 0; it < HF_MAXIT; ++it) {
    if (myrec[it] >= 0)
      perm[cnt[myrec[it] >> 17] + myp[it]] = myrec[it] & 0x1FFFF;
  }
}

// ===========================================================================
// K3: gather_e — one wave per hyperedge, 8-deep ILP (r17/r19 proven form;
// r20 A/B: 2 edges/wave regressed — degree ~50 already amortizes overhead).
// ===========================================================================
__global__ __launch_bounds__(256) void gather_e_kernel(
    const bf16* __restrict__ Xl, const int* __restrict__ perm,
    const int* __restrict__ offs, const float* __restrict__ degE,
    const float* __restrict__ W_edge, bf16* __restrict__ Xe, int E) {
  const int gtid = blockIdx.x * 256 + threadIdx.x;
  const int e    = gtid >> 6;
  const int lane = gtid & 63;
  if (e >= E) return;

  const int beg = offs[e];
  const int end = offs[e + 1];
  float acc = 0.f;

  for (int base = beg; base < end; base += 64) {
    const int n = min(64, end - base);
    const int idx = (lane < n) ? __builtin_nontemporal_load(&perm[base + lane]) : 0;
    int jj = 0;
    for (; jj + 8 <= n; jj += 8) {
      const bf16* p0 = &Xl[(size_t)__shfl(idx, jj + 0, 64) * 64 + lane];
      const bf16* p1 = &Xl[(size_t)__shfl(idx, jj + 1, 64) * 64 + lane];
      const bf16* p2 = &Xl[(size_t)__shfl(idx, jj + 2, 64) * 64 + lane];
      const bf16* p3 = &Xl[(size_t)__shfl(idx, jj + 3, 64) * 64 + lane];
      const bf16* p4 = &Xl[(size_t)__shfl(idx, jj + 4, 64) * 64 + lane];
      const bf16* p5 = &Xl[(size_t)__shfl(idx, jj + 5, 64) * 64 + lane];
      const bf16* p6 = &Xl[(size_t)__shfl(idx, jj + 6, 64) * 64 + lane];
      const bf16* p7 = &Xl[(size_t)__shfl(idx, jj + 7, 64) * 64 + lane];
      const float f0 = bf2f(*p0), f1 = bf2f(*p1), f2 = bf2f(*p2), f3 = bf2f(*p3);
      const float f4 = bf2f(*p4), f5 = bf2f(*p5), f6 = bf2f(*p6), f7 = bf2f(*p7);
      acc += ((f0 + f1) + (f2 + f3)) + ((f4 + f5) + (f6 + f7));
    }
    for (; jj + 4 <= n; jj += 4) {
      const int v0 = __shfl(idx, jj + 0, 64);
      const int v1 = __shfl(idx, jj + 1, 64);
      const int v2 = __shfl(idx, jj + 2, 64);
      const int v3 = __shfl(idx, jj + 3, 64);
      const float f0 = bf2f(Xl[(size_t)v0 * 64 + lane]);
      const float f1 = bf2f(Xl[(size_t)v1 * 64 + lane]);
      const float f2 = bf2f(Xl[(size_t)v2 * 64 + lane]);
      const float f3 = bf2f(Xl[(size_t)v3 * 64 + lane]);
      acc += (f0 + f1) + (f2 + f3);
    }
    for (; jj < n; ++jj) {
      const int v = __shfl(idx, jj, 64);
      acc += bf2f(Xl[(size_t)v * 64 + lane]);
    }
  }
  const float s = degE[e] * W_edge[e];
  Xe[(size_t)e * 64 + lane] = __float2bfloat16(acc * s);
}

// ===========================================================================
// K4: gather_v — one wave per 4 CONSECUTIVE nodes (r19 proven optimum;
// r20 A/B: 8/wave regressed — past the amortization knee). One lane-indexed
// load covers 5 offs boundaries + degV; shared 64-entry perm chunk.
// ===========================================================================
__global__ __launch_bounds__(256) void gather_v_kernel(
    const bf16* __restrict__ Xe, const int* __restrict__ perm,
    const int* __restrict__ offs, const float* __restrict__ degV,
    float* __restrict__ out, int N, int E) {
  const int wave = (blockIdx.x * 256 + threadIdx.x) >> 6;
  const int lane = threadIdx.x & 63;
  const int v0   = wave * 4;
  if (v0 >= N) return;
  const int nv = min(4, N - v0);

  const int   offv = (lane <= nv) ? offs[E + v0 + lane] : 0;
  const float dv   = (lane < nv) ? degV[v0 + lane] : 0.f;
  const int wend = __shfl(offv, nv, 64);
  int cb  = __shfl(offv, 0, 64);
  int idx = (cb + lane < wend) ? __builtin_nontemporal_load(&perm[cb + lane]) : 0;

  for (int k = 0; k < nv; ++k) {
    const int beg = __shfl(offv, k, 64);
    const int end = __shfl(offv, k + 1, 64);
    float acc = 0.f;
    int j = beg;
    while (j < end) {
      if (j - cb >= 64) {
        cb += 64;
        idx = (cb + lane < wend) ? __builtin_nontemporal_load(&perm[cb + lane]) : 0;
        continue;   // re-check (handles multi-chunk skips)
      }
      const int lim = min(end, cb + 64);
      for (; j + 4 <= lim; j += 4) {
        const int e0 = __shfl(idx, j - cb + 0, 64);
        const int e1 = __shfl(idx, j - cb + 1, 64);
        const int e2 = __shfl(idx, j - cb + 2, 64);
        const int e3 = __shfl(idx, j - cb + 3, 64);
        const float f0 = bf2f(Xe[(size_t)e0 * 64 + lane]);
        const float f1 = bf2f(Xe[(size_t)e1 * 64 + lane]);
        const float f2 = bf2f(Xe[(size_t)e2 * 64 + lane]);
        const float f3 = bf2f(Xe[(size_t)e3 * 64 + lane]);
        acc += (f0 + f1) + (f2 + f3);
      }
      for (; j < lim; ++j) {
        const int e = __shfl(idx, j - cb, 64);
        acc += bf2f(Xe[(size_t)e * 64 + lane]);
      }
    }
    const float d = __shfl(dv, k, 64);
    __builtin_nontemporal_store(acc * d, &out[(size_t)(v0 + k) * 64 + lane]);
  }
}

// ===========================================================================
extern "C" void kernel_launch(void* const* d_in, const int* in_sizes, int n_in,
                              void* d_out, int out_size, void* d_ws, size_t ws_size,
                              hipStream_t stream) {
  const float* X      = (const float*)d_in[0];
  const int*   vertex = (const int*)d_in[1];
  const int*   edges  = (const int*)d_in[2];
  const float* W      = (const float*)d_in[3];
  const float* degE   = (const float*)d_in[4];
  const float* degV   = (const float*)d_in[5];
  const float* W_edge = (const float*)d_in[6];
  float* out = (float*)d_out;

  const int nnz = in_sizes[1];
  const int E   = in_sizes[4];
  const int N   = in_sizes[5];
  const int M   = E + N;

  const int nEB = (E + (1 << EB_BITS) - 1) >> EB_BITS;
  const int nVB = (N + (1 << VB_BITS) - 1) >> VB_BITS;
  const int KB  = nEB + nVB;

  // caps: <= HF_MAXIT*1024 (histfill register carry) and %4==0 (int4 loads)
  int capE = (nnz / nEB) * 3 / 2 + 256;
  int capV = (nnz / nVB) * 3 / 2 + 256;
  if (capE > HF_MAXIT * 1024) capE = HF_MAXIT * 1024;
  if (capV > HF_MAXIT * 1024) capV = HF_MAXIT * 1024;
  capE = (capE + 3) & ~3;
  capV = (capV + 3) & ~3;
  const size_t rec_total = (size_t)nEB * capE + (size_t)nVB * capV;

  char* p = (char*)d_ws;
  auto alloc = [&](size_t bytes) -> void* {
    void* r = (void*)p;
    p += (bytes + 255) & ~(size_t)255;
    return r;
  };
  int*  offs    = (int*)alloc((size_t)(M + 1) * 4);
  int*  gcursor = (int*)alloc(MAXBK * 4);
  int*  perm    = (int*)alloc((size_t)2 * nnz * 4);   //  8 MB
  int*  records = (int*)alloc(rec_total * 4);         // ~12 MB (live w/ Xl)
  bf16* Xl      = (bf16*)alloc((size_t)N * 64 * 2);   // 12.8 MB
  bf16* Xe      = (bf16*)alloc((size_t)E * 64 * 2);   //  2.56 MB

  const int f1blocks = (nnz + F1_ITEMS - 1) / F1_ITEMS;
  const int ntiles   = (N + 63) / 64;
  const int GB       = ntiles < 512 ? ntiles : 512;
  const int vwaves   = (N + 3) / 4;                   // gather_v waves

  zero_gc_kernel<<<1, MAXBK, 0, stream>>>(gcursor);
  fused1_kernel<<<GB + f1blocks, 256, 0, stream>>>(
      vertex, edges, gcursor, records, X, W, Xl,
      nnz, KB, nEB, capE, capV, N, ntiles, GB);
  histfill_kernel<<<KB, 1024, 0, stream>>>(records, gcursor, offs, perm,
                                           nEB, capE, capV, E, M, KB, 2 * nnz);
  gather_e_kernel<<<(E + 3) / 4, 256, 0, stream>>>(Xl, perm, offs, degE, W_edge, Xe, E);
  gather_v_kernel<<<(vwaves + 3) / 4, 256, 0, stream>>>(Xe, perm, offs, degV, out, N, E);
}